// Round 1
// baseline (2676.847 us; speedup 1.0000x reference)
//
#include <hip/hip_runtime.h>
#include <cstdint>

#define Dd   256
#define HID  64
#define Pp   2
#define BSz  1024
#define BB   16    // b rows per block
#define TT   16    // t cols per block
#define JC   8     // j chunk staged per iteration
#define WPAD 68    // padded i-stride for ws tiles (bank rotate, 16B-aligned rows)
#define XPAD 260   // padded row stride for xs (bank rotate, 16B-aligned rows)
#define BPAD 68
#define NT   256

__global__ __launch_bounds__(NT, 2)
void fused_mlp_kernel(const float* __restrict__ x,
                      const float* __restrict__ M,
                      const float* __restrict__ W0,
                      const float* __restrict__ b0,
                      const float* __restrict__ W1,
                      const float* __restrict__ b1,
                      const float* __restrict__ W2,
                      const float* __restrict__ b2,
                      float* __restrict__ out)
{
    __shared__ float xs[BB * XPAD];        // 16.6 KB  x rows
    __shared__ float ws[JC * TT * WPAD];   // 34.8 KB  weight chunk (reused L0/L1/L2)
    __shared__ float bia0[TT * BPAD];      // 4.3 KB
    __shared__ float bia1[TT * BPAD];      // 4.3 KB

    const int tid = threadIdx.x;
    const int tl  = tid & (TT - 1);   // t within tile
    const int bl  = tid >> 4;         // b within tile

    // bijective XCD-contiguous swizzle: 1024 blocks, 8 XCDs, 128 each.
    // Each XCD covers 2 t-tiles -> 2 MB W0 slice fits 4 MB per-XCD L2.
    const int orig = blockIdx.x;
    const int wg   = (orig & 7) * (1024 / 8) + (orig >> 3);
    const int b0r  = (wg & 63) * BB;      // b-tile base
    const int t0   = (wg >> 6) * TT;      // t-tile base
    const int tglob = t0 + tl;

    // ---- stage x rows (vectorized, padded rows) ----
    {
        const float4* xg = reinterpret_cast<const float4*>(x + (size_t)b0r * Dd);
        for (int k = tid; k < BB * (Dd / 4); k += NT) {
            int row = k >> 6, c4 = k & 63;
            float4 v = xg[row * (Dd / 4) + c4];
            float* dst = xs + row * XPAD + c4 * 4;
            dst[0] = v.x; dst[1] = v.y; dst[2] = v.z; dst[3] = v.w;
        }
    }
    for (int k = tid; k < TT * HID; k += NT) {
        int t = k >> 6, i = k & 63;
        bia0[t * BPAD + i] = b0[(size_t)t0 * HID + k];
        bia1[t * BPAD + i] = b1[(size_t)t0 * HID + k];
    }

    float acc[HID];
#pragma unroll
    for (int i = 0; i < HID; ++i) acc[i] = 0.0f;

    // =======================================================================
    // Layer 0: acc[i] = sum_j W0[tglob,i,j] * (j==tglob ? 0 : M[b,j,tglob]*x[b,j])
    // =======================================================================
    const float* Mrow = M + (size_t)(b0r + bl) * Dd * Dd + tglob;

    for (int jc = 0; jc < Dd / JC; ++jc) {
        const int j0 = jc * JC;

        // issue M loads early; coalesced: 16 consecutive t per bl-group
        float mreg[JC];
#pragma unroll
        for (int jj = 0; jj < JC; ++jj)
            mreg[jj] = Mrow[(size_t)(j0 + jj) * Dd];

        __syncthreads();   // previous chunk's ws reads done
        // stage ws[j'][t][i] = W0[(t0+t), i, j0+j']
#pragma unroll
        for (int k = 0; k < (TT * HID) / NT; ++k) {
            int p = tid + k * NT;
            int t = p >> 6, i = p & 63;
            const float* g = W0 + ((size_t)(t0 + t) * HID + i) * Dd + j0;
            float4 v0 = *reinterpret_cast<const float4*>(g);
            float4 v1 = *reinterpret_cast<const float4*>(g + 4);
            float* dst = ws + t * WPAD + i;
            dst[0 * TT * WPAD] = v0.x; dst[1 * TT * WPAD] = v0.y;
            dst[2 * TT * WPAD] = v0.z; dst[3 * TT * WPAD] = v0.w;
            dst[4 * TT * WPAD] = v1.x; dst[5 * TT * WPAD] = v1.y;
            dst[6 * TT * WPAD] = v1.z; dst[7 * TT * WPAD] = v1.w;
        }
        __syncthreads();

#pragma unroll
        for (int jj = 0; jj < JC; ++jj) {
            const int j = j0 + jj;
            float xm = mreg[jj] * xs[bl * XPAD + j];
            xm = (j == tglob) ? 0.0f : xm;        // adj = ones - eye
            const float4* wrow =
                reinterpret_cast<const float4*>(ws + (jj * TT + tl) * WPAD);
#pragma unroll
            for (int i4 = 0; i4 < HID / 4; ++i4) {
                float4 w = wrow[i4];
                acc[i4 * 4 + 0] = fmaf(w.x, xm, acc[i4 * 4 + 0]);
                acc[i4 * 4 + 1] = fmaf(w.y, xm, acc[i4 * 4 + 1]);
                acc[i4 * 4 + 2] = fmaf(w.z, xm, acc[i4 * 4 + 2]);
                acc[i4 * 4 + 3] = fmaf(w.w, xm, acc[i4 * 4 + 3]);
            }
        }
    }

    // bias + leaky_relu (slope 0.01)
#pragma unroll
    for (int i = 0; i < HID; ++i) {
        float h = acc[i] + bia0[tl * BPAD + i];
        acc[i] = (h >= 0.0f) ? h : 0.01f * h;
    }

    // =======================================================================
    // Layer 1: acc2[i] = sum_j W1[tglob,i,j] * h[j]
    // =======================================================================
    float acc2[HID];
#pragma unroll
    for (int i = 0; i < HID; ++i) acc2[i] = 0.0f;

#pragma unroll   // MUST fully unroll: acc[j0+jj] needs compile-time index
    for (int jc = 0; jc < HID / JC; ++jc) {
        const int j0 = jc * JC;
        __syncthreads();
#pragma unroll
        for (int k = 0; k < (TT * HID) / NT; ++k) {
            int p = tid + k * NT;
            int t = p >> 6, i = p & 63;
            const float* g = W1 + ((size_t)(t0 + t) * HID + i) * HID + j0;
            float4 v0 = *reinterpret_cast<const float4*>(g);
            float4 v1 = *reinterpret_cast<const float4*>(g + 4);
            float* dst = ws + t * WPAD + i;
            dst[0 * TT * WPAD] = v0.x; dst[1 * TT * WPAD] = v0.y;
            dst[2 * TT * WPAD] = v0.z; dst[3 * TT * WPAD] = v0.w;
            dst[4 * TT * WPAD] = v1.x; dst[5 * TT * WPAD] = v1.y;
            dst[6 * TT * WPAD] = v1.z; dst[7 * TT * WPAD] = v1.w;
        }
        __syncthreads();

#pragma unroll
        for (int jj = 0; jj < JC; ++jj) {
            const float hv = acc[j0 + jj];
            const float4* wrow =
                reinterpret_cast<const float4*>(ws + (jj * TT + tl) * WPAD);
#pragma unroll
            for (int i4 = 0; i4 < HID / 4; ++i4) {
                float4 w = wrow[i4];
                acc2[i4 * 4 + 0] = fmaf(w.x, hv, acc2[i4 * 4 + 0]);
                acc2[i4 * 4 + 1] = fmaf(w.y, hv, acc2[i4 * 4 + 1]);
                acc2[i4 * 4 + 2] = fmaf(w.z, hv, acc2[i4 * 4 + 2]);
                acc2[i4 * 4 + 3] = fmaf(w.w, hv, acc2[i4 * 4 + 3]);
            }
        }
    }

    // bias + leaky -> h2 back into acc
#pragma unroll
    for (int i = 0; i < HID; ++i) {
        float h = acc2[i] + bia1[tl * BPAD + i];
        acc[i] = (h >= 0.0f) ? h : 0.01f * h;
    }

    // =======================================================================
    // Layer 2: out[b,t,p] = sum_j W2[t,p,j]*h2[j] + b2[t,p]
    // =======================================================================
    __syncthreads();
    for (int k = tid; k < TT * Pp * HID; k += NT) {
        int t = k >> 7, r = k & 127;
        int p = r >> 6, j = r & 63;
        ws[t * (2 * WPAD) + p * WPAD + j] = W2[(size_t)t0 * Pp * HID + k];
    }
    __syncthreads();

    float o0 = 0.0f, o1 = 0.0f;
    const float4* wp0 = reinterpret_cast<const float4*>(ws + tl * (2 * WPAD));
    const float4* wp1 = reinterpret_cast<const float4*>(ws + tl * (2 * WPAD) + WPAD);
#pragma unroll
    for (int i4 = 0; i4 < HID / 4; ++i4) {
        float4 wa = wp0[i4];
        float4 wb = wp1[i4];
        o0 = fmaf(wa.x, acc[i4 * 4 + 0], o0);
        o0 = fmaf(wa.y, acc[i4 * 4 + 1], o0);
        o0 = fmaf(wa.z, acc[i4 * 4 + 2], o0);
        o0 = fmaf(wa.w, acc[i4 * 4 + 3], o0);
        o1 = fmaf(wb.x, acc[i4 * 4 + 0], o1);
        o1 = fmaf(wb.y, acc[i4 * 4 + 1], o1);
        o1 = fmaf(wb.z, acc[i4 * 4 + 2], o1);
        o1 = fmaf(wb.w, acc[i4 * 4 + 3], o1);
    }
    const float2 bb = *reinterpret_cast<const float2*>(b2 + (size_t)tglob * Pp);
    float2 o;
    o.x = o0 + bb.x;
    o.y = o1 + bb.y;
    *reinterpret_cast<float2*>(out + ((size_t)(b0r + bl) * Dd + tglob) * Pp) = o;
}

extern "C" void kernel_launch(void* const* d_in, const int* in_sizes, int n_in,
                              void* d_out, int out_size, void* d_ws, size_t ws_size,
                              hipStream_t stream)
{
    // setup_inputs order: x, M, adj, W0, b0, W1, b1, W2, b2
    const float* x  = (const float*)d_in[0];
    const float* M  = (const float*)d_in[1];
    // d_in[2] = adj (ones - eye): folded into the (j==t) predicate, unused.
    const float* W0 = (const float*)d_in[3];
    const float* b0 = (const float*)d_in[4];
    const float* W1 = (const float*)d_in[5];
    const float* b1 = (const float*)d_in[6];
    const float* W2 = (const float*)d_in[7];
    const float* b2 = (const float*)d_in[8];
    float* out = (float*)d_out;

    const int grid = (BSz / BB) * (Dd / TT);   // 1024 blocks
    fused_mlp_kernel<<<grid, NT, 0, stream>>>(x, M, W0, b0, W1, b1, W2, b2, out);
}

// Round 3
// 615.625 us; speedup vs baseline: 4.3482x; 4.3482x over previous
//
#include <hip/hip_runtime.h>
#include <cstdint>

#define Dd   256
#define HID  64
#define Pp   2
#define BSz  1024
#define BB   16    // b per block
#define TT   16    // t per block
#define JC   8     // j chunk
#define NT   512
#define WSTR 68    // ws row stride (floats): [JC][TT][WSTR], 2-way banks only
#define XSTR 20    // xm row stride (floats): [JC][TT][XSTR], 16B-aligned rows

__global__ __launch_bounds__(NT, 4)   // cap VGPR at 128 -> 2 blocks/CU with 45KB LDS
void fused_mlp_v2(const float* __restrict__ x,
                  const float* __restrict__ M,
                  const float* __restrict__ W0,
                  const float* __restrict__ b0,
                  const float* __restrict__ W1,
                  const float* __restrict__ b1,
                  const float* __restrict__ W2,
                  const float* __restrict__ b2,
                  float* __restrict__ out)
{
    __shared__ float ws[JC * TT * WSTR];   // 34,816 B  weight chunk [j][t][i]
    __shared__ float xm[JC * TT * XSTR];   // 10,240 B  masked inputs [j][t][b]

    const int tid = threadIdx.x;

    // ---- compute-role indices: thread owns (t=tc, b=bg*4..+3, i=ig*8..+7) ----
    const int ig = tid & 7;
    const int bg = (tid >> 3) & 3;
    const int tc = tid >> 5;              // wave = 2 consecutive t's
    // ---- staging-role indices for M/xm ----
    const int t4 = tid & 3;               // t quad (float4 of M along t)
    const int bs = (tid >> 2) & 15;
    const int jg = tid >> 6;              // j within chunk
    // ---- staging-role indices for weights ----
    const int jq = tid & 1;               // float4-half of the 8-j chunk
    const int iw = (tid >> 1) & 63;
    const int tw = tid >> 7;              // t = s*4 + tw over 4 rounds

    // bijective XCD swizzle (1024 % 8 == 0): each XCD -> 2 t-tiles -> 2MB W0 in its L2
    const int orig = blockIdx.x;
    const int wgid = (orig & 7) * 128 + (orig >> 3);
    const int b0r  = (wgid & 63) * BB;
    const int t0   = (wgid >> 6) * TT;

    const float* Mp = M + (size_t)(b0r + bs) * (Dd * Dd) + t0 + t4 * 4;
    const float* xp = x + (size_t)(b0r + bs) * Dd;

    float acc[32];
#pragma unroll
    for (int k = 0; k < 32; ++k) acc[k] = 0.0f;

    // =======================================================================
    // Layer 0: acc[b',i] += W0[t,i,j] * (M[b,j,t]*x[b,j]*(j!=t))
    // =======================================================================
#pragma unroll 1
    for (int jc = 0; jc < Dd / JC; ++jc) {
        const int j0 = jc * JC;
        // ---- global loads for this chunk (issued before barrier) ----
        const float4 mv = *reinterpret_cast<const float4*>(Mp + (size_t)(j0 + jg) * Dd);
        const float  xv = xp[j0 + jg];
        float4 wv[4];
#pragma unroll
        for (int s = 0; s < 4; ++s) {
            const int t = s * 4 + tw;
            wv[s] = *reinterpret_cast<const float4*>(
                W0 + ((size_t)(t0 + t) * HID + iw) * Dd + j0 + jq * 4);
        }

        __syncthreads();   // previous chunk fully consumed

        // xm[j][t][b] = M*x, diagonal zeroed (adj = ones - eye)
        {
            const int jglob = j0 + jg;
            const int tb = t0 + t4 * 4;
            float* dst = xm + (jg * TT + t4 * 4) * XSTR + bs;
            dst[0 * XSTR] = (jglob == tb + 0) ? 0.0f : mv.x * xv;
            dst[1 * XSTR] = (jglob == tb + 1) ? 0.0f : mv.y * xv;
            dst[2 * XSTR] = (jglob == tb + 2) ? 0.0f : mv.z * xv;
            dst[3 * XSTR] = (jglob == tb + 3) ? 0.0f : mv.w * xv;
        }
        // ws[j][t][i]
#pragma unroll
        for (int s = 0; s < 4; ++s) {
            const int t = s * 4 + tw;
            float* dst = ws + ((jq * 4) * TT + t) * WSTR + iw;
            dst[0 * TT * WSTR] = wv[s].x;
            dst[1 * TT * WSTR] = wv[s].y;
            dst[2 * TT * WSTR] = wv[s].z;
            dst[3 * TT * WSTR] = wv[s].w;
        }
        __syncthreads();

        // ---- compute: 3 b128 LDS reads per 32 FMAs ----
        const float* wsrow = ws + tc * WSTR + ig * 8;
        const float* xmrow = xm + tc * XSTR + bg * 4;
#pragma unroll
        for (int jj = 0; jj < JC; ++jj) {
            const float4 a  = *reinterpret_cast<const float4*>(xmrow + jj * TT * XSTR);
            const float4 wA = *reinterpret_cast<const float4*>(wsrow + jj * TT * WSTR);
            const float4 wB = *reinterpret_cast<const float4*>(wsrow + jj * TT * WSTR + 4);
            const float av[4]  = {a.x, a.y, a.z, a.w};
            const float wvv[8] = {wA.x, wA.y, wA.z, wA.w, wB.x, wB.y, wB.z, wB.w};
#pragma unroll
            for (int rb = 0; rb < 4; ++rb)
#pragma unroll
                for (int ii = 0; ii < 8; ++ii)
                    acc[rb * 8 + ii] = fmaf(av[rb], wvv[ii], acc[rb * 8 + ii]);
        }
    }

    // bias + leaky_relu -> h[rb][jj] (this thread's i-slice becomes a j-slice)
    float h[4][8];
    {
        const float4 ba = *reinterpret_cast<const float4*>(b0 + (size_t)(t0 + tc) * HID + ig * 8);
        const float4 bb = *reinterpret_cast<const float4*>(b0 + (size_t)(t0 + tc) * HID + ig * 8 + 4);
        const float bv[8] = {ba.x, ba.y, ba.z, ba.w, bb.x, bb.y, bb.z, bb.w};
#pragma unroll
        for (int rb = 0; rb < 4; ++rb)
#pragma unroll
            for (int ii = 0; ii < 8; ++ii) {
                const float v = acc[rb * 8 + ii] + bv[ii];
                h[rb][ii] = (v >= 0.0f) ? v : 0.01f * v;
            }
    }

    // =======================================================================
    // Layer 1: acc2[b',i] += W1[t,i,j] * h[b,t,j]; h exchanged via in-wave shfl
    // =======================================================================
    float acc2[32];
#pragma unroll
    for (int k = 0; k < 32; ++k) acc2[k] = 0.0f;

    const int laneBase = tid & 56;   // (bg, t-parity) bits of the lane id

#pragma unroll 1
    for (int jc = 0; jc < HID / JC; ++jc) {
        float4 wv[4];
#pragma unroll
        for (int s = 0; s < 4; ++s) {
            const int t = s * 4 + tw;
            wv[s] = *reinterpret_cast<const float4*>(
                W1 + ((size_t)(t0 + t) * HID + iw) * HID + jc * JC + jq * 4);
        }
        __syncthreads();
#pragma unroll
        for (int s = 0; s < 4; ++s) {
            const int t = s * 4 + tw;
            float* dst = ws + ((jq * 4) * TT + t) * WSTR + iw;
            dst[0 * TT * WSTR] = wv[s].x;
            dst[1 * TT * WSTR] = wv[s].y;
            dst[2 * TT * WSTR] = wv[s].z;
            dst[3 * TT * WSTR] = wv[s].w;
        }
        __syncthreads();

        const float* wsrow = ws + tc * WSTR + ig * 8;
#pragma unroll
        for (int jj = 0; jj < JC; ++jj) {
            const float4 wA = *reinterpret_cast<const float4*>(wsrow + jj * TT * WSTR);
            const float4 wB = *reinterpret_cast<const float4*>(wsrow + jj * TT * WSTR + 4);
            const float wvv[8] = {wA.x, wA.y, wA.z, wA.w, wB.x, wB.y, wB.z, wB.w};
            // h[b, j=jc*8+jj] lives in the lane with ig==jc of the same (bg,t)
            const float h0 = __shfl(h[0][jj], laneBase + jc, 64);
            const float h1 = __shfl(h[1][jj], laneBase + jc, 64);
            const float h2 = __shfl(h[2][jj], laneBase + jc, 64);
            const float h3 = __shfl(h[3][jj], laneBase + jc, 64);
            const float hv[4] = {h0, h1, h2, h3};
#pragma unroll
            for (int rb = 0; rb < 4; ++rb)
#pragma unroll
                for (int ii = 0; ii < 8; ++ii)
                    acc2[rb * 8 + ii] = fmaf(hv[rb], wvv[ii], acc2[rb * 8 + ii]);
        }
    }

    // bias + leaky -> h2
    float h2[4][8];
    {
        const float4 ba = *reinterpret_cast<const float4*>(b1 + (size_t)(t0 + tc) * HID + ig * 8);
        const float4 bb = *reinterpret_cast<const float4*>(b1 + (size_t)(t0 + tc) * HID + ig * 8 + 4);
        const float bv[8] = {ba.x, ba.y, ba.z, ba.w, bb.x, bb.y, bb.z, bb.w};
#pragma unroll
        for (int rb = 0; rb < 4; ++rb)
#pragma unroll
            for (int ii = 0; ii < 8; ++ii) {
                const float v = acc2[rb * 8 + ii] + bv[ii];
                h2[rb][ii] = (v >= 0.0f) ? v : 0.01f * v;
            }
    }

    // =======================================================================
    // Layer 2: out[b,t,p] = sum_j W2[t,p,j]*h2[j] + b2[t,p]; butterfly over ig
    // =======================================================================
    const float* w2p = W2 + (size_t)(t0 + tc) * Pp * HID + ig * 8;
    const float4 wa0 = *reinterpret_cast<const float4*>(w2p);
    const float4 wa1 = *reinterpret_cast<const float4*>(w2p + 4);
    const float4 wb0 = *reinterpret_cast<const float4*>(w2p + HID);
    const float4 wb1 = *reinterpret_cast<const float4*>(w2p + HID + 4);
    const float w2v0[8] = {wa0.x, wa0.y, wa0.z, wa0.w, wa1.x, wa1.y, wa1.z, wa1.w};
    const float w2v1[8] = {wb0.x, wb0.y, wb0.z, wb0.w, wb1.x, wb1.y, wb1.z, wb1.w};

    float po[4][2];
#pragma unroll
    for (int rb = 0; rb < 4; ++rb) { po[rb][0] = 0.0f; po[rb][1] = 0.0f; }
#pragma unroll
    for (int rb = 0; rb < 4; ++rb)
#pragma unroll
        for (int jj = 0; jj < 8; ++jj) {
            po[rb][0] = fmaf(w2v0[jj], h2[rb][jj], po[rb][0]);
            po[rb][1] = fmaf(w2v1[jj], h2[rb][jj], po[rb][1]);
        }
#pragma unroll
    for (int d = 1; d < 8; d <<= 1)
#pragma unroll
        for (int rb = 0; rb < 4; ++rb) {
            po[rb][0] += __shfl_xor(po[rb][0], d, 64);
            po[rb][1] += __shfl_xor(po[rb][1], d, 64);
        }

    if (ig == 0) {
        const float2 b2v = *reinterpret_cast<const float2*>(b2 + (size_t)(t0 + tc) * Pp);
#pragma unroll
        for (int rb = 0; rb < 4; ++rb) {
            float2 o;
            o.x = po[rb][0] + b2v.x;
            o.y = po[rb][1] + b2v.y;
            *reinterpret_cast<float2*>(
                out + ((size_t)(b0r + bg * 4 + rb) * Dd + (t0 + tc)) * Pp) = o;
        }
    }
}

extern "C" void kernel_launch(void* const* d_in, const int* in_sizes, int n_in,
                              void* d_out, int out_size, void* d_ws, size_t ws_size,
                              hipStream_t stream)
{
    // setup_inputs order: x, M, adj, W0, b0, W1, b1, W2, b2
    const float* x  = (const float*)d_in[0];
    const float* M  = (const float*)d_in[1];
    // d_in[2] = adj (ones - eye): folded into the (j==t) predicate, unused.
    const float* W0 = (const float*)d_in[3];
    const float* b0 = (const float*)d_in[4];
    const float* W1 = (const float*)d_in[5];
    const float* b1 = (const float*)d_in[6];
    const float* W2 = (const float*)d_in[7];
    const float* b2 = (const float*)d_in[8];
    float* out = (float*)d_out;

    const int grid = (BSz / BB) * (Dd / TT);   // 1024 blocks
    fused_mlp_v2<<<grid, NT, 0, stream>>>(x, M, W0, b0, W1, b1, W2, b2, out);
}

// Round 4
// 578.765 us; speedup vs baseline: 4.6251x; 1.0637x over previous
//
#include <hip/hip_runtime.h>
#include <hip/hip_bf16.h>
#include <cstdint>

#define Dd   256
#define HID  64
#define Pp   2
#define BSz  1024
#define BB   16     // b per block
#define TT   16     // t per block
#define NT   512    // 8 waves
#define XMS  36     // xm row stride (floats): [16t][16b][36] -> balanced banks, 16B-aligned
#define HBS  68     // hbuf row stride (floats): [8t][16b][68]

typedef __attribute__((ext_vector_type(8))) short bf16x8;
typedef __attribute__((ext_vector_type(4))) float f32x4;

__device__ __forceinline__ short f2bf(float f) {
    return __builtin_bit_cast(short, __float2bfloat16(f));
}
__device__ __forceinline__ float bf2f(short s) {
    return __bfloat162float(__builtin_bit_cast(__hip_bfloat16, s));
}

// split 8 fp32 into hi/lo bf16 fragments (hi + lo reproduces a to ~2^-17 rel)
__device__ __forceinline__ void split8(const float a[8], bf16x8& hi, bf16x8& lo) {
#pragma unroll
    for (int e = 0; e < 8; ++e) {
        const short h = f2bf(a[e]);
        hi[e] = h;
        lo[e] = f2bf(a[e] - bf2f(h));
    }
}

__global__ __launch_bounds__(NT, 4)   // VGPR cap 128 -> 2 blocks/CU
void fused_mlp_v3(const float* __restrict__ x,  const float* __restrict__ M,
                  const float* __restrict__ W0, const float* __restrict__ b0,
                  const float* __restrict__ W1, const float* __restrict__ b1,
                  const float* __restrict__ W2, const float* __restrict__ b2,
                  float* __restrict__ out)
{
    // 36,864 B; layer0: xm[16t][16b][36j-pad]; passes: hbuf[8t][16b][68i-pad]
    __shared__ float smem[TT * BB * XMS];

    const int tid  = threadIdx.x;
    const int lane = tid & 63;
    const int w    = tid >> 6;          // wave 0..7
    const int ln15 = lane & 15;
    const int lg   = lane >> 4;         // 0..3

    // bijective XCD swizzle (1024 blocks, 8 XCDs): each XCD sees 2 t-tiles ->
    // its 2MB fp32 W0 slice stays L2-resident.
    const int orig = blockIdx.x;
    const int wgid = (orig & 7) * 128 + (orig >> 3);
    const int b0r  = (wgid & 63) * BB;
    const int t0   = (wgid >> 6) * TT;

    // staging roles: thread -> (b=bst, j=jloc); reads M[b][j][t0..t0+15] = one 64B line
    const int jloc = tid & 31;
    const int bst  = tid >> 5;          // 0..15
    const float* Mp = M + ((size_t)(b0r + bst) * Dd) * Dd + t0;
    const float* xp = x + (size_t)(b0r + bst) * Dd;

    f32x4 acc[2][4];
#pragma unroll
    for (int a = 0; a < 2; ++a)
#pragma unroll
        for (int b = 0; b < 4; ++b)
            acc[a][b] = f32x4{0.f, 0.f, 0.f, 0.f};

    // ---- prefetch chunk 0 ----
    float4 m0, m1, m2, m3; float xv;
    {
        const float* mp = Mp + (size_t)jloc * Dd;
        m0 = *(const float4*)(mp + 0);  m1 = *(const float4*)(mp + 4);
        m2 = *(const float4*)(mp + 8);  m3 = *(const float4*)(mp + 12);
        xv = xp[jloc];
    }

    // =======================================================================
    // Layer 0: 8 K-chunks of 32.  split-bf16 MFMA 16x16x32.
    // =======================================================================
#pragma unroll 1
    for (int kc = 0; kc < 8; ++kc) {
        __syncthreads();   // previous chunk's xm fully consumed

        // issue next-chunk loads (latency hides under this chunk's MFMAs)
        const int kn = (kc < 7) ? kc + 1 : 7;
        float4 n0, n1, n2, n3; float xn;
        {
            const float* mp = Mp + (size_t)(kn * 32 + jloc) * Dd;
            n0 = *(const float4*)(mp + 0);  n1 = *(const float4*)(mp + 4);
            n2 = *(const float4*)(mp + 8);  n3 = *(const float4*)(mp + 12);
            xn = xp[kn * 32 + jloc];
        }

        // stage xm[t][b][j] fp32, masked (adj = ones - eye)
        {
            const int jg = kc * 32 + jloc;
            float* xrow = smem + bst * XMS + jloc;
            const float mv[16] = {m0.x, m0.y, m0.z, m0.w, m1.x, m1.y, m1.z, m1.w,
                                  m2.x, m2.y, m2.z, m2.w, m3.x, m3.y, m3.z, m3.w};
#pragma unroll
            for (int tt = 0; tt < 16; ++tt) {
                float v = mv[tt] * xv;
                v = (jg == t0 + tt) ? 0.0f : v;
                xrow[(size_t)tt * BB * XMS] = v;
            }
        }
        __syncthreads();

        // compute: wave w owns t = t0 + 2w, 2w+1; all 64 i (4 tiles of 16)
#pragma unroll
        for (int tp = 0; tp < 2; ++tp) {
            const int tloc = 2 * w + tp;
            float af[8];
            const float* ap = smem + ((size_t)(tloc * BB + ln15)) * XMS + lg * 8;
            *(float4*)&af[0] = *(const float4*)ap;
            *(float4*)&af[4] = *(const float4*)(ap + 4);
            bf16x8 ahi, alo; split8(af, ahi, alo);

            const float* wrow = W0 + (size_t)(t0 + tloc) * HID * Dd + kc * 32 + lg * 8;
#pragma unroll
            for (int it = 0; it < 4; ++it) {
                float bf[8];
                const float* bp = wrow + (size_t)(it * 16 + ln15) * Dd;
                *(float4*)&bf[0] = *(const float4*)bp;
                *(float4*)&bf[4] = *(const float4*)(bp + 4);
                bf16x8 bhi, blo; split8(bf, bhi, blo);
                acc[tp][it] = __builtin_amdgcn_mfma_f32_16x16x32_bf16(ahi, bhi, acc[tp][it], 0, 0, 0);
                acc[tp][it] = __builtin_amdgcn_mfma_f32_16x16x32_bf16(ahi, blo, acc[tp][it], 0, 0, 0);
                acc[tp][it] = __builtin_amdgcn_mfma_f32_16x16x32_bf16(alo, bhi, acc[tp][it], 0, 0, 0);
            }
        }
        m0 = n0; m1 = n1; m2 = n2; m3 = n3; xv = xn;
    }

    // ---- bias + leaky_relu -> h regs (D layout: b=(lg*4+r), i=it*16+ln15) ----
    float hreg[2][4][4];   // [tp][it][r]
#pragma unroll
    for (int tp = 0; tp < 2; ++tp) {
        const int t = t0 + 2 * w + tp;
#pragma unroll
        for (int it = 0; it < 4; ++it) {
            const float bv = b0[(size_t)t * HID + it * 16 + ln15];
#pragma unroll
            for (int r = 0; r < 4; ++r) {
                const float v = acc[tp][it][r] + bv;
                hreg[tp][it][r] = (v >= 0.f) ? v : 0.01f * v;
            }
        }
    }

    // =======================================================================
    // Layers 1+2 in two t-half passes (hbuf reuses smem)
    // =======================================================================
#pragma unroll 1
    for (int pass = 0; pass < 2; ++pass) {
        __syncthreads();   // smem free (xm dead / previous pass consumed)

        if ((w >> 2) == pass) {   // waves 0-3 hold t-local 0-7; waves 4-7 hold 8-15
            const int wl = w & 3;
#pragma unroll
            for (int tp = 0; tp < 2; ++tp) {
                const int tlp = 2 * wl + tp;
#pragma unroll
                for (int it = 0; it < 4; ++it)
#pragma unroll
                    for (int r = 0; r < 4; ++r)
                        smem[(size_t)(tlp * BB + lg * 4 + r) * HBS + it * 16 + ln15] =
                            hreg[tp][it][r];
            }
        }
        __syncthreads();

        // layer 1: wave w computes t = t0 + pass*8 + w  (MFMA, K=64 in 2 chunks)
        const int t = t0 + pass * 8 + w;
        f32x4 acc2[4];
#pragma unroll
        for (int it = 0; it < 4; ++it) acc2[it] = f32x4{0.f, 0.f, 0.f, 0.f};

#pragma unroll
        for (int kc2 = 0; kc2 < 2; ++kc2) {
            float af[8];
            const float* ap = smem + (size_t)(w * BB + ln15) * HBS + kc2 * 32 + lg * 8;
            *(float4*)&af[0] = *(const float4*)ap;
            *(float4*)&af[4] = *(const float4*)(ap + 4);
            bf16x8 ahi, alo; split8(af, ahi, alo);

            const float* w1row = W1 + (size_t)t * HID * HID + kc2 * 32 + lg * 8;
#pragma unroll
            for (int it = 0; it < 4; ++it) {
                float bf[8];
                const float* bp = w1row + (size_t)(it * 16 + ln15) * HID;
                *(float4*)&bf[0] = *(const float4*)bp;
                *(float4*)&bf[4] = *(const float4*)(bp + 4);
                bf16x8 bhi, blo; split8(bf, bhi, blo);
                acc2[it] = __builtin_amdgcn_mfma_f32_16x16x32_bf16(ahi, bhi, acc2[it], 0, 0, 0);
                acc2[it] = __builtin_amdgcn_mfma_f32_16x16x32_bf16(ahi, blo, acc2[it], 0, 0, 0);
                acc2[it] = __builtin_amdgcn_mfma_f32_16x16x32_bf16(alo, bhi, acc2[it], 0, 0, 0);
            }
        }

        // layer 2: h2 = leaky(acc2 + b1); out[b,t,p] = sum_i' W2[t,p,i'] h2[b,i'] + b2
        float po0[4] = {0.f, 0.f, 0.f, 0.f};
        float po1[4] = {0.f, 0.f, 0.f, 0.f};
#pragma unroll
        for (int it = 0; it < 4; ++it) {
            const float b1v = b1[(size_t)t * HID + it * 16 + ln15];
            const float w2a = W2[(size_t)t * Pp * HID + 0 * HID + it * 16 + ln15];
            const float w2b = W2[(size_t)t * Pp * HID + 1 * HID + it * 16 + ln15];
#pragma unroll
            for (int r = 0; r < 4; ++r) {
                float v = acc2[it][r] + b1v;
                v = (v >= 0.f) ? v : 0.01f * v;
                po0[r] = fmaf(w2a, v, po0[r]);
                po1[r] = fmaf(w2b, v, po1[r]);
            }
        }
        // reduce over the 16 i'-lanes (low 4 lane bits)
#pragma unroll
        for (int d = 1; d < 16; d <<= 1)
#pragma unroll
            for (int r = 0; r < 4; ++r) {
                po0[r] += __shfl_xor(po0[r], d, 64);
                po1[r] += __shfl_xor(po1[r], d, 64);
            }
        if (ln15 == 0) {
            const float2 b2v = *(const float2*)(b2 + (size_t)t * Pp);
#pragma unroll
            for (int r = 0; r < 4; ++r) {
                const int bg = lg * 4 + r;
                float2 o;
                o.x = po0[r] + b2v.x;
                o.y = po1[r] + b2v.y;
                *(float2*)(out + ((size_t)(b0r + bg) * Dd + t) * Pp) = o;
            }
        }
    }
}

extern "C" void kernel_launch(void* const* d_in, const int* in_sizes, int n_in,
                              void* d_out, int out_size, void* d_ws, size_t ws_size,
                              hipStream_t stream)
{
    // setup_inputs order: x, M, adj, W0, b0, W1, b1, W2, b2
    const float* x  = (const float*)d_in[0];
    const float* M  = (const float*)d_in[1];
    // d_in[2] = adj (ones - eye): folded into the (j==t) predicate, unused.
    const float* W0 = (const float*)d_in[3];
    const float* b0 = (const float*)d_in[4];
    const float* W1 = (const float*)d_in[5];
    const float* b1 = (const float*)d_in[6];
    const float* W2 = (const float*)d_in[7];
    const float* b2 = (const float*)d_in[8];
    float* out = (float*)d_out;

    const int grid = (BSz / BB) * (Dd / TT);   // 1024 blocks
    fused_mlp_v3<<<grid, NT, 0, stream>>>(x, M, W0, b0, W1, b1, W2, b2, out);
}